// Round 1
// baseline (10.294 us; speedup 1.0000x reference)
//
#include <hip/hip_runtime.h>

// output[b,f] = max_t ( x[b,t,f]==1 ? T-1-t : 0 )  ==  T-1-t_first  (first spike)
// Early-exit scan from t=0: once every neuron owned by a lane has spiked, stop.
// Deterministic for fixed input.

__global__ __launch_bounds__(64) void first_spike_kernel(const float* __restrict__ x,
                                                         float* __restrict__ out,
                                                         int T, int F, int blocks_per_b) {
    const int b  = blockIdx.x / blocks_per_b;
    const int fb = blockIdx.x % blocks_per_b;
    const int f0 = (fb * 64 + threadIdx.x) * 4;   // 4 consecutive features per thread

    const float4* p = reinterpret_cast<const float4*>(
        x + (size_t)b * T * F + f0);
    const int strideVec = F / 4;   // float4 elements per timestep row

    float o0 = 0.f, o1 = 0.f, o2 = 0.f, o3 = 0.f;
    bool  d0 = false, d1 = false, d2 = false, d3 = false;

    constexpr int CHUNK = 8;       // T==2048 is divisible by 8
    for (int t0 = 0; t0 < T; t0 += CHUNK) {
        // issue CHUNK independent loads to amortize memory latency
        float4 v[CHUNK];
#pragma unroll
        for (int k = 0; k < CHUNK; ++k)
            v[k] = p[(size_t)(t0 + k) * strideVec];

#pragma unroll
        for (int k = 0; k < CHUNK; ++k) {
            const float tv = (float)(T - 1 - (t0 + k));
            if (!d0 && v[k].x == 1.0f) { o0 = tv; d0 = true; }
            if (!d1 && v[k].y == 1.0f) { o1 = tv; d1 = true; }
            if (!d2 && v[k].z == 1.0f) { o2 = tv; d2 = true; }
            if (!d3 && v[k].w == 1.0f) { o3 = tv; d3 = true; }
        }
        if (d0 & d1 & d2 & d3) break;   // lane done; wave exits when all lanes done
    }

    float4* o = reinterpret_cast<float4*>(out + (size_t)b * F + f0);
    *o = make_float4(o0, o1, o2, o3);
}

extern "C" void kernel_launch(void* const* d_in, const int* in_sizes, int n_in,
                              void* d_out, int out_size, void* d_ws, size_t ws_size,
                              hipStream_t stream) {
    const float* x  = (const float*)d_in[0];
    float*       out = (float*)d_out;

    const int T = 2048;
    const int F = 1024;
    const int B = in_sizes[0] / (T * F);   // 64

    const int blocks_per_b = F / (64 * 4); // 4 blocks of 64 threads cover F=1024
    dim3 grid(B * blocks_per_b);           // 256 blocks -> one wave per CU
    dim3 block(64);

    hipLaunchKernelGGL(first_spike_kernel, grid, block, 0, stream,
                       x, out, T, F, blocks_per_b);
}

// Round 2
// 9.776 us; speedup vs baseline: 1.0529x; 1.0529x over previous
//
#include <hip/hip_runtime.h>

// output[b,f] = max_t ( x[b,t,f]==1 ? T-1-t : 0 )  ==  T-1-t_first  (first spike)
// Early-exit scan from t=0: once every neuron owned by a lane has spiked, stop.
// CHUNK=16: P(a lane's 4 neurons not all fired within 16 steps) ~ 4*2^-16,
// so ~all waves finish in ONE dependent memory round. Deterministic for fixed input.

__global__ __launch_bounds__(64) void first_spike_kernel(const float* __restrict__ x,
                                                         float* __restrict__ out,
                                                         int T, int F, int blocks_per_b) {
    const int b  = blockIdx.x / blocks_per_b;
    const int fb = blockIdx.x % blocks_per_b;
    const int f0 = (fb * 64 + threadIdx.x) * 4;   // 4 consecutive features per thread

    const float4* p = reinterpret_cast<const float4*>(
        x + (size_t)b * T * F + f0);
    const int strideVec = F / 4;   // float4 elements per timestep row

    float o0 = 0.f, o1 = 0.f, o2 = 0.f, o3 = 0.f;
    bool  d0 = false, d1 = false, d2 = false, d3 = false;

    constexpr int CHUNK = 16;      // T==2048 divisible by 16
    for (int t0 = 0; t0 < T; t0 += CHUNK) {
        // issue CHUNK independent loads to amortize memory latency (one round)
        float4 v[CHUNK];
#pragma unroll
        for (int k = 0; k < CHUNK; ++k)
            v[k] = p[(size_t)(t0 + k) * strideVec];

#pragma unroll
        for (int k = 0; k < CHUNK; ++k) {
            const float tv = (float)(T - 1 - (t0 + k));
            if (!d0 && v[k].x == 1.0f) { o0 = tv; d0 = true; }
            if (!d1 && v[k].y == 1.0f) { o1 = tv; d1 = true; }
            if (!d2 && v[k].z == 1.0f) { o2 = tv; d2 = true; }
            if (!d3 && v[k].w == 1.0f) { o3 = tv; d3 = true; }
        }
        if (d0 & d1 & d2 & d3) break;   // lane done; wave exits when all lanes done
    }

    float4* o = reinterpret_cast<float4*>(out + (size_t)b * F + f0);
    *o = make_float4(o0, o1, o2, o3);
}

extern "C" void kernel_launch(void* const* d_in, const int* in_sizes, int n_in,
                              void* d_out, int out_size, void* d_ws, size_t ws_size,
                              hipStream_t stream) {
    const float* x  = (const float*)d_in[0];
    float*       out = (float*)d_out;

    const int T = 2048;
    const int F = 1024;
    const int B = in_sizes[0] / (T * F);   // 64

    const int blocks_per_b = F / (64 * 4); // 4 blocks of 64 threads cover F=1024
    dim3 grid(B * blocks_per_b);           // 256 blocks -> one wave per CU
    dim3 block(64);

    hipLaunchKernelGGL(first_spike_kernel, grid, block, 0, stream,
                       x, out, T, F, blocks_per_b);
}